// Round 14
// baseline (104.034 us; speedup 1.0000x reference)
//
#include <hip/hip_runtime.h>
#include <hip/hip_bf16.h>

#define B_ 2
#define T_ 2048
#define DM_ 1024
#define H_ 16
#define DH_ 64
// softmax computed in exp2 units: fold log2(e)/sqrt(1024) into Q
#define QSCALE 0.045084220027780106f

typedef unsigned short u16;
typedef unsigned int u32;
typedef __attribute__((ext_vector_type(2))) unsigned int u32x2;
typedef __attribute__((ext_vector_type(4))) unsigned int u32x4;
typedef __attribute__((ext_vector_type(4))) float f32x4v;
typedef __attribute__((ext_vector_type(8))) short bf16x8;
typedef __attribute__((ext_vector_type(4))) float f32x4;
typedef __attribute__((ext_vector_type(16))) float f32x16;

__device__ __forceinline__ u16 f2bf(float f) {
    u32 u = __float_as_uint(f);
    return (u16)((u + 0x7FFF + ((u >> 16) & 1)) >> 16);
}
__device__ __forceinline__ float bf2f(u16 h) {
    return __uint_as_float(((u32)h) << 16);
}
__device__ __forceinline__ float exp2_fast(float x) {
    float r;
    asm("v_exp_f32 %0, %1" : "=v"(r) : "v"(x));
    return r;
}
__device__ __forceinline__ u32 cvtpk_bf16(float lo, float hi) {
    u32 r;
    asm("v_cvt_pk_bf16_f32 %0, %1, %2" : "=v"(r) : "v"(lo), "v"(hi));
    return r;
}

// LDS rows are 128B with 16B-granule XOR swizzle: byte = row*128 + ((c16 ^ (row&7))<<4)
__device__ __forceinline__ const bf16x8* frag_at(const u16* base, int row, int c16) {
    return (const bf16x8*)((const char*)base + row * 128 + ((c16 ^ (row & 7)) << 4));
}

// split 8 f32 -> hi/lo packed u32x4 pairs
__device__ __forceinline__ void split8(const f32x4v a, const f32x4v b,
                                       u32x4* hi, u32x4* lo) {
    u32x4 h, l;
    h[0] = cvtpk_bf16(a[0], a[1]);
    h[1] = cvtpk_bf16(a[2], a[3]);
    h[2] = cvtpk_bf16(b[0], b[1]);
    h[3] = cvtpk_bf16(b[2], b[3]);
    const float l0 = a[0] - __uint_as_float(h[0] << 16);
    const float l1 = a[1] - __uint_as_float(h[0] & 0xFFFF0000u);
    const float l2 = a[2] - __uint_as_float(h[1] << 16);
    const float l3 = a[3] - __uint_as_float(h[1] & 0xFFFF0000u);
    const float l4 = b[0] - __uint_as_float(h[2] << 16);
    const float l5 = b[1] - __uint_as_float(h[2] & 0xFFFF0000u);
    const float l6 = b[2] - __uint_as_float(h[3] << 16);
    const float l7 = b[3] - __uint_as_float(h[3] & 0xFFFF0000u);
    l[0] = cvtpk_bf16(l0, l1);
    l[1] = cvtpk_bf16(l2, l3);
    l[2] = cvtpk_bf16(l4, l5);
    l[3] = cvtpk_bf16(l6, l7);
    *hi = h; *lo = l;
}

// ---------------- QKV projection via MFMA (split-bf16, fp32-grade) ----------------
// Self-splits Wq/Wk/Wv into LDS (no pre-split kernel needed).
__global__ __launch_bounds__(256) void qkv_mfma(
    const float* __restrict__ x,
    const float* __restrict__ Wq, const float* __restrict__ bq,
    const float* __restrict__ Wk, const float* __restrict__ bk,
    const float* __restrict__ Wv, const float* __restrict__ bv,
    u16* __restrict__ Q, u16* __restrict__ K, u16* __restrict__ VT)
{
    __shared__ u16 Ws[6 * 4096];   // 48KB: Wqh,Wql,Wkh,Wkl,Wvh,Wvl (swizzled rows)

    const int tid = threadIdx.x;
    const int wid = tid >> 6;
    const int lane = tid & 63;
    const int li = lane & 15, g = lane >> 4;

    const int bh = blockIdx.x >> 4;
    const int t0 = (blockIdx.x & 15) * 128;
    const int b = bh >> 4, h = bh & 15;
    const int tw0 = t0 + wid * 32;

    // ---- self-split W staging: 1536 (r,c16) slots, 6 per thread, mat = j>>1 ----
    #pragma unroll
    for (int j = 0; j < 6; ++j) {
        const int idx = (j & 1) * 256 + tid;     // 0..511 within matrix
        const int r = idx >> 3, c16 = idx & 7;
        const float* src = (j < 2) ? Wq : (j < 4) ? Wk : Wv;
        const float* p = src + r * 64 + c16 * 8;
        const f32x4v a = *(const f32x4v*)p;
        const f32x4v bb = *(const f32x4v*)(p + 4);
        u32x4 hv, lv;
        split8(a, bb, &hv, &lv);
        const int dst = r * 128 + ((c16 ^ (r & 7)) << 4);
        const int mat = j >> 1;
        *(u32x4*)((char*)Ws + (2 * mat) * 8192 + dst) = hv;
        *(u32x4*)((char*)Ws + (2 * mat + 1) * 8192 + dst) = lv;
    }

    const float* xb = x + ((size_t)b * T_) * DM_ + h * 64;
    f32x4v xr[2][2][2];
    #pragma unroll
    for (int mt = 0; mt < 2; ++mt)
        #pragma unroll
        for (int kt = 0; kt < 2; ++kt) {
            const float* p = xb + (size_t)(tw0 + 16 * mt + li) * DM_ + kt * 32 + g * 8;
            xr[mt][kt][0] = *(const f32x4v*)p;
            xr[mt][kt][1] = *(const f32x4v*)(p + 4);
        }

    float bq_r[4], bk_r[4], bv_r[4][4];
    #pragma unroll
    for (int nt = 0; nt < 4; ++nt) { bq_r[nt] = bq[16 * nt + li]; bk_r[nt] = bk[16 * nt + li]; }
    #pragma unroll
    for (int vd = 0; vd < 4; ++vd)
        #pragma unroll
        for (int rg = 0; rg < 4; ++rg) bv_r[vd][rg] = bv[16 * vd + 4 * g + rg];

    __syncthreads();   // W split staged (lgkm) + x loads landed

    bf16x8 xhf[2][2], xlf[2][2];
    #pragma unroll
    for (int mt = 0; mt < 2; ++mt)
        #pragma unroll
        for (int kt = 0; kt < 2; ++kt) {
            u32x4 hv, lv;
            split8(xr[mt][kt][0], xr[mt][kt][1], &hv, &lv);
            xhf[mt][kt] = __builtin_bit_cast(bf16x8, hv);
            xlf[mt][kt] = __builtin_bit_cast(bf16x8, lv);
        }

    const u16* Wqh = Ws;
    const u16* Wql = Ws + 4096;
    const u16* Wkh = Ws + 8192;
    const u16* Wkl = Ws + 12288;
    const u16* Wvh = Ws + 16384;
    const u16* Wvl = Ws + 20480;

    const size_t qk_base = ((size_t)bh * T_) * DH_;

    // ---- Q ----
    {
        f32x4 acc[2][4];
        #pragma unroll
        for (int mt = 0; mt < 2; ++mt)
            #pragma unroll
            for (int nt = 0; nt < 4; ++nt) acc[mt][nt] = (f32x4){0.f, 0.f, 0.f, 0.f};
        #pragma unroll
        for (int nt = 0; nt < 4; ++nt)
            #pragma unroll
            for (int kt = 0; kt < 2; ++kt) {
                const bf16x8 wh = *frag_at(Wqh, 16 * nt + li, 4 * kt + g);
                const bf16x8 wl = *frag_at(Wql, 16 * nt + li, 4 * kt + g);
                #pragma unroll
                for (int mt = 0; mt < 2; ++mt) {
                    acc[mt][nt] = __builtin_amdgcn_mfma_f32_16x16x32_bf16(xhf[mt][kt], wh, acc[mt][nt], 0, 0, 0);
                    acc[mt][nt] = __builtin_amdgcn_mfma_f32_16x16x32_bf16(xlf[mt][kt], wh, acc[mt][nt], 0, 0, 0);
                    acc[mt][nt] = __builtin_amdgcn_mfma_f32_16x16x32_bf16(xhf[mt][kt], wl, acc[mt][nt], 0, 0, 0);
                }
            }
        #pragma unroll
        for (int mt = 0; mt < 2; ++mt)
            #pragma unroll
            for (int rg = 0; rg < 4; ++rg) {
                const int t = tw0 + 16 * mt + 4 * g + rg;
                #pragma unroll
                for (int nt = 0; nt < 4; ++nt)
                    Q[qk_base + (size_t)t * DH_ + 16 * nt + li] =
                        f2bf((acc[mt][nt][rg] + bq_r[nt]) * QSCALE);
            }
    }

    // ---- K ----
    {
        f32x4 acc[2][4];
        #pragma unroll
        for (int mt = 0; mt < 2; ++mt)
            #pragma unroll
            for (int nt = 0; nt < 4; ++nt) acc[mt][nt] = (f32x4){0.f, 0.f, 0.f, 0.f};
        #pragma unroll
        for (int nt = 0; nt < 4; ++nt)
            #pragma unroll
            for (int kt = 0; kt < 2; ++kt) {
                const bf16x8 wh = *frag_at(Wkh, 16 * nt + li, 4 * kt + g);
                const bf16x8 wl = *frag_at(Wkl, 16 * nt + li, 4 * kt + g);
                #pragma unroll
                for (int mt = 0; mt < 2; ++mt) {
                    acc[mt][nt] = __builtin_amdgcn_mfma_f32_16x16x32_bf16(xhf[mt][kt], wh, acc[mt][nt], 0, 0, 0);
                    acc[mt][nt] = __builtin_amdgcn_mfma_f32_16x16x32_bf16(xlf[mt][kt], wh, acc[mt][nt], 0, 0, 0);
                    acc[mt][nt] = __builtin_amdgcn_mfma_f32_16x16x32_bf16(xhf[mt][kt], wl, acc[mt][nt], 0, 0, 0);
                }
            }
        #pragma unroll
        for (int mt = 0; mt < 2; ++mt)
            #pragma unroll
            for (int rg = 0; rg < 4; ++rg) {
                const int t = tw0 + 16 * mt + 4 * g + rg;
                #pragma unroll
                for (int nt = 0; nt < 4; ++nt)
                    K[qk_base + (size_t)t * DH_ + 16 * nt + li] =
                        f2bf(acc[mt][nt][rg] + bk_r[nt]);
            }
    }

    // ---- V (swapped) -> V^T ----
    {
        f32x4 acc[4][2];
        #pragma unroll
        for (int vd = 0; vd < 4; ++vd)
            #pragma unroll
            for (int tc = 0; tc < 2; ++tc) acc[vd][tc] = (f32x4){0.f, 0.f, 0.f, 0.f};
        #pragma unroll
        for (int vd = 0; vd < 4; ++vd)
            #pragma unroll
            for (int kt = 0; kt < 2; ++kt) {
                const bf16x8 ah = *frag_at(Wvh, 16 * vd + li, 4 * kt + g);
                const bf16x8 al = *frag_at(Wvl, 16 * vd + li, 4 * kt + g);
                #pragma unroll
                for (int tc = 0; tc < 2; ++tc) {
                    acc[vd][tc] = __builtin_amdgcn_mfma_f32_16x16x32_bf16(ah, xhf[tc][kt], acc[vd][tc], 0, 0, 0);
                    acc[vd][tc] = __builtin_amdgcn_mfma_f32_16x16x32_bf16(al, xhf[tc][kt], acc[vd][tc], 0, 0, 0);
                    acc[vd][tc] = __builtin_amdgcn_mfma_f32_16x16x32_bf16(ah, xlf[tc][kt], acc[vd][tc], 0, 0, 0);
                }
            }
        u16* VTb = VT + (size_t)bh * DH_ * T_;
        #pragma unroll
        for (int vd = 0; vd < 4; ++vd)
            #pragma unroll
            for (int rg = 0; rg < 4; ++rg) {
                const int d = 16 * vd + 4 * g + rg;
                #pragma unroll
                for (int tc = 0; tc < 2; ++tc)
                    VTb[(size_t)d * T_ + tw0 + 16 * tc + li] =
                        f2bf(acc[vd][tc][rg] + bv_r[vd][rg]);
            }
    }
}

// ---------------- fused: MFMA flash attention + Wp split ----------------
// grid = 4608: flat%9==0 -> attn block aid=flat/9 (XCD grouping preserved:
// 9*aid mod 8 == aid mod 8); else -> Wp-split block (overlaps with attn).
__global__ __launch_bounds__(256) void attn_mfma(
    const u16* __restrict__ Q, const u16* __restrict__ K,
    const u16* __restrict__ VT, u16* __restrict__ Ah, u16* __restrict__ Al,
    const float* __restrict__ Wp, u16* __restrict__ Wh, u16* __restrict__ Wl)
{
    __shared__ char smem[65536];

    const int flat = blockIdx.x;
    const int m9 = flat % 9;
    const int tid = threadIdx.x;

    if (m9 != 0) {
        // ---- Wp split block (block-uniform branch; no LDS, no barrier) ----
        const int wsb = flat - (flat / 9) - 1;      // 0..4095
        const int i = wsb * 256 + tid;
        const float w = Wp[i];
        const u16 hi = f2bf(w);
        Wh[i] = hi;
        Wl[i] = f2bf(w - bf2f(hi));
        return;
    }

    const int aid = flat / 9;                        // 0..511
    const int wid = tid >> 6;              // 0..3
    const int lane = tid & 63;
    const int l = lane & 31, h = lane >> 5;
    const int bh = (aid & 7) + ((aid >> 7) << 3);
    const int qx = (aid >> 3) & 15;
    const int q0 = qx * 128 + wid * 32;

    const size_t bhoff = (size_t)bh * T_ * DH_;

    // Q fragments (B operand): qf[kt] holds Q[q0+l][16kt+8h .. +7]
    bf16x8 qf[4];
    {
        const u16* Qp = Q + bhoff + (size_t)(q0 + l) * DH_ + 8 * h;
        #pragma unroll
        for (int kt = 0; kt < 4; ++kt)
            qf[kt] = *(const bf16x8*)(Qp + 16 * kt);
    }

    f32x16 o0 = {}, o1 = {};       // O^T[d][q=l]
    f32x16 sA, sB, sC, sD;         // S^T sub-blocks kv 0-31,32-63,64-95,96-127
    float l_part = 0.f;

    // hoisted ds_read lane bases
    const char* ldsR[4];
    #pragma unroll
    for (int j = 0; j < 4; ++j)
        ldsR[j] = smem + l * 128 + ((((2 * j + h) ^ (l & 7))) << 4);

    // staging pointers (pre-swizzled source, linear LDS dest)
    const int sl_r = lane >> 3;
    const int sl_c = (lane & 7) ^ sl_r;
    const char* kgp = (const char*)(K + bhoff) + (32 * wid + sl_r) * 128 + (sl_c << 4);
    const char* vgp = (const char*)(VT + (size_t)bh * DH_ * T_) + (size_t)(16 * wid + sl_r) * (T_ * 2) + (sl_c << 4);
    const int kdst = 32 * wid * 128 + lane * 16;
    const int vdst = 16 * wid * 128 + lane * 16;

#define STAGE(KB_, VB_)                                                                  \
    {                                                                                    \
        _Pragma("unroll")                                                                \
        for (int j = 0; j < 4; ++j)                                                      \
            __builtin_amdgcn_global_load_lds(                                            \
                (const __attribute__((address_space(1))) u32*)(kgp + j * 1024),          \
                (__attribute__((address_space(3))) u32*)(smem + (KB_) + kdst + j * 1024),\
                16, 0, 0);                                                               \
        __builtin_amdgcn_global_load_lds(                                                \
            (const __attribute__((address_space(1))) u32*)vgp,                           \
            (__attribute__((address_space(3))) u32*)(smem + (VB_) + vdst), 16, 0, 0);    \
        __builtin_amdgcn_global_load_lds(                                                \
            (const __attribute__((address_space(1))) u32*)(vgp + 8 * T_ * 2),            \
            (__attribute__((address_space(3))) u32*)(smem + (VB_) + vdst + 1024), 16, 0, 0); \
        __builtin_amdgcn_global_load_lds(                                                \
            (const __attribute__((address_space(1))) u32*)(vgp + 128),                   \
            (__attribute__((address_space(3))) u32*)(smem + (VB_) + 8192 + vdst), 16, 0, 0); \
        __builtin_amdgcn_global_load_lds(                                                \
            (const __attribute__((address_space(1))) u32*)(vgp + 8 * T_ * 2 + 128),      \
            (__attribute__((address_space(3))) u32*)(smem + (VB_) + 8192 + vdst + 1024), 16, 0, 0); \
        kgp += 16384; vgp += 256;                                                        \
    }

#define QK(KB_, S, c)                                                                    \
    {                                                                                    \
        S = (f32x16){};                                                                  \
        _Pragma("unroll")                                                                \
        for (int kt = 0; kt < 4; ++kt) {                                                 \
            const bf16x8 kf = *(const bf16x8*)(ldsR[kt] + (KB_) + (c) * 4096);           \
            S = __builtin_amdgcn_mfma_f32_32x32x16_bf16(kf, qf[kt], S, 0, 0, 0);         \
        }                                                                                \
    }

#define SMPV(S, c, VB_)                                                                  \
    {                                                                                    \
        float lacc = 0.f;                                                                \
        _Pragma("unroll")                                                                \
        for (int r = 0; r < 16; ++r) { S[r] = exp2_fast(S[r]); lacc += S[r]; }           \
        l_part += lacc;                                                                  \
        __builtin_amdgcn_s_setprio(1);                                                   \
        _Pragma("unroll")                                                                \
        for (int ktl = 0; ktl < 2; ++ktl) {                                              \
            const int rb = ktl * 8;                                                      \
            u32 w0 = cvtpk_bf16(S[rb + 0], S[rb + 1]);                                   \
            u32 w1 = cvtpk_bf16(S[rb + 2], S[rb + 3]);                                   \
            u32 w2 = cvtpk_bf16(S[rb + 4], S[rb + 5]);                                   \
            u32 w3 = cvtpk_bf16(S[rb + 6], S[rb + 7]);                                   \
            asm("v_permlane32_swap_b32 %0, %1" : "+v"(w0), "+v"(w2));                    \
            asm("v_permlane32_swap_b32 %0, %1" : "+v"(w1), "+v"(w3));                    \
            u32x4 pw; pw[0] = w0; pw[1] = w1; pw[2] = w2; pw[3] = w3;                    \
            const bf16x8 pf = __builtin_bit_cast(bf16x8, pw);                            \
            const char* vb = ldsR[2 * ((c) & 1) + ktl] + (VB_) + ((c) >> 1) * 8192;      \
            const bf16x8 vf0 = *(const bf16x8*)vb;                                       \
            const bf16x8 vf1 = *(const bf16x8*)(vb + 4096);                              \
            o0 = __builtin_amdgcn_mfma_f32_32x32x16_bf16(vf0, pf, o0, 0, 0, 0);          \
            o1 = __builtin_amdgcn_mfma_f32_32x32x16_bf16(vf1, pf, o1, 0, 0, 0);          \
        }                                                                                \
        __builtin_amdgcn_s_setprio(0);                                                   \
    }

#define ATTN_ITER(KB_, VB_, PKB_, PVB_, DO_PREF)                                         \
    {                                                                                    \
        __syncthreads();                                                                 \
        if (DO_PREF) STAGE(PKB_, PVB_);                                                  \
        __builtin_amdgcn_s_setprio(1);                                                   \
        QK(KB_, sA, 0); QK(KB_, sB, 1); QK(KB_, sC, 2); QK(KB_, sD, 3);                  \
        __builtin_amdgcn_s_setprio(0);                                                   \
        SMPV(sA, 0, VB_); SMPV(sB, 1, VB_); SMPV(sC, 2, VB_); SMPV(sD, 3, VB_);          \
    }

    STAGE(0, 32768);
    for (int it = 0; it < 16; it += 2) {
        ATTN_ITER(0, 32768, 16384, 49152, true);
        ATTN_ITER(16384, 49152, 0, 32768, (it + 2 < 16));
    }
#undef ATTN_ITER
#undef SMPV
#undef QK
#undef STAGE

    const float lt = l_part + __shfl_xor(l_part, 32);
    const float inv = 1.0f / lt;

    __syncthreads();   // done with K/V LDS; reuse as per-wave epilogue scratch

    char* ehi = smem + wid * 8192;
    char* elo = ehi + 4096;
    #pragma unroll
    for (int db = 0; db < 2; ++db) {
        #pragma unroll
        for (int rr = 0; rr < 4; ++rr) {
            float v0, v1, v2, v3;
            if (db == 0) {
                v0 = o0[4 * rr + 0] * inv; v1 = o0[4 * rr + 1] * inv;
                v2 = o0[4 * rr + 2] * inv; v3 = o0[4 * rr + 3] * inv;
            } else {
                v0 = o1[4 * rr + 0] * inv; v1 = o1[4 * rr + 1] * inv;
                v2 = o1[4 * rr + 2] * inv; v3 = o1[4 * rr + 3] * inv;
            }
            u32x2 wh, wl;
            wh.x = cvtpk_bf16(v0, v1);
            wh.y = cvtpk_bf16(v2, v3);
            const float r0 = v0 - __uint_as_float(wh.x << 16);
            const float r1 = v1 - __uint_as_float(wh.x & 0xFFFF0000u);
            const float r2 = v2 - __uint_as_float(wh.y << 16);
            const float r3 = v3 - __uint_as_float(wh.y & 0xFFFF0000u);
            wl.x = cvtpk_bf16(r0, r1);
            wl.y = cvtpk_bf16(r2, r3);
            const int byteoff = l * 128 + (((4 * db + rr) ^ (l & 7)) << 4) + 8 * h;
            *(u32x2*)(ehi + byteoff) = wh;
            *(u32x2*)(elo + byteoff) = wl;
        }
    }
    // per-wave private region: lgkmcnt ordering suffices, no barrier

    const int b = bh >> 4, head = bh & 15;
    const int sub = lane & 7;
    const int row8 = lane >> 3;
    #pragma unroll
    for (int rr = 0; rr < 4; ++rr) {
        const int row = 8 * rr + row8;
        const int byteoff = row * 128 + ((sub ^ row8) << 4);
        const size_t gidx = ((size_t)b * T_ + q0 + row) * DM_ + head * 64 + sub * 8;
        *(u32x4*)(Ah + gidx) = *(const u32x4*)(ehi + byteoff);
        *(u32x4*)(Al + gidx) = *(const u32x4*)(elo + byteoff);
    }
}

// ---------------- Output projection: split-bf16 MFMA GEMM, 8 waves, dbuf ----------------
// 1-D grid 256, XCD-swizzled: col strip = flat&7 (stays on one XCD -> W L2-resident).
__global__ __launch_bounds__(512) void proj_mfma(
    const u16* __restrict__ Ah, const u16* __restrict__ Al,
    const u16* __restrict__ Wh, const u16* __restrict__ Wl,
    const float* __restrict__ bp, float* __restrict__ out)
{
    __shared__ char smem[131072];  // 2 x {Ah,Al,Wh,Wl} of 128x64 bf16 (16KB each)

    const int tid = threadIdx.x;
    const int wid = tid >> 6;      // 0..7
    const int lane = tid & 63;
    const int li = lane & 15, g = lane >> 4;
    const int flat = blockIdx.x;
    const int row0 = (flat >> 3) * 128, col0 = (flat & 7) * 128;

    const int mat = wid >> 1, half = wid & 1;
    const char* gsrc;
    if (mat == 0)      gsrc = (const char*)(Ah + (size_t)row0 * DM_);
    else if (mat == 1) gsrc = (const char*)(Al + (size_t)row0 * DM_);
    else if (mat == 2) gsrc = (const char*)(Wh + (size_t)col0 * DM_);
    else               gsrc = (const char*)(Wl + (size_t)col0 * DM_);
    const int r_local = half * 64 + (lane >> 3);
    const int c16s = (lane & 7) ^ (lane >> 3);
    const char* gp0 = gsrc + (size_t)r_local * (DM_ * 2) + (c16s << 4);
    const int ldst0 = mat * 16384 + half * 8192;

#define PSTAGE(BUF, STEP)                                                                \
    {                                                                                    \
        _Pragma("unroll")                                                                \
        for (int j = 0; j < 8; ++j) {                                                    \
            __builtin_amdgcn_global_load_lds(                                            \
                (const __attribute__((address_space(1))) u32*)(gp0 + (size_t)(STEP) * 128 + (size_t)j * (8 * DM_ * 2)), \
                (__attribute__((address_space(3))) u32*)(smem + (BUF) + ldst0 + j * 1024),\
                16, 0, 0);                                                               \
        }                                                                                \
    }

    const int wr = wid >> 1, wc = wid & 1;

    f32x4 acc[2][4];
    #pragma unroll
    for (int m = 0; m < 2; ++m)
        #pragma unroll
        for (int n = 0; n < 4; ++n) acc[m][n] = (f32x4){0.f, 0.f, 0.f, 0.f};

    PSTAGE(0, 0);
    for (int step = 0; step < 16; ++step) {
        const int buf = (step & 1) * 65536;
        __syncthreads();
        if (step < 15) PSTAGE(buf ^ 65536, step + 1);

        const u16* pAh = (const u16*)(smem + buf);
        const u16* pAl = (const u16*)(smem + buf + 16384);
        const u16* pWh = (const u16*)(smem + buf + 32768);
        const u16* pWl = (const u16*)(smem + buf + 49152);

        __builtin_amdgcn_s_setprio(1);
        #pragma unroll
        for (int kt = 0; kt < 2; ++kt) {
            bf16x8 ah[2], al[2], wh[4], wl[4];
            #pragma unroll
            for (int m = 0; m < 2; ++m) {
                ah[m] = *frag_at(pAh, wr * 32 + m * 16 + li, kt * 4 + g);
                al[m] = *frag_at(pAl, wr * 32 + m * 16 + li, kt * 4 + g);
            }
            #pragma unroll
            for (int n = 0; n < 4; ++n) {
                wh[n] = *frag_at(pWh, wc * 64 + n * 16 + li, kt * 4 + g);
                wl[n] = *frag_at(pWl, wc * 64 + n * 16 + li, kt * 4 + g);
            }
            #pragma unroll
            for (int m = 0; m < 2; ++m)
                #pragma unroll
                for (int n = 0; n < 4; ++n) {
                    acc[m][n] = __builtin_amdgcn_mfma_f32_16x16x32_bf16(ah[m], wh[n], acc[m][n], 0, 0, 0);
                    acc[m][n] = __builtin_amdgcn_mfma_f32_16x16x32_bf16(al[m], wh[n], acc[m][n], 0, 0, 0);
                    acc[m][n] = __builtin_amdgcn_mfma_f32_16x16x32_bf16(ah[m], wl[n], acc[m][n], 0, 0, 0);
                }
        }
        __builtin_amdgcn_s_setprio(0);
    }
#undef PSTAGE

    const int orow = row0 + wr * 32;
    const int ocol = col0 + wc * 64;
    float bias[4];
    #pragma unroll
    for (int n = 0; n < 4; ++n) bias[n] = bp[ocol + n * 16 + li];
    #pragma unroll
    for (int m = 0; m < 2; ++m)
        #pragma unroll
        for (int n = 0; n < 4; ++n)
            #pragma unroll
            for (int q = 0; q < 4; ++q)
                out[(size_t)(orow + m * 16 + g * 4 + q) * DM_ + ocol + n * 16 + li] =
                    acc[m][n][q] + bias[n];
}

extern "C" void kernel_launch(void* const* d_in, const int* in_sizes, int n_in,
                              void* d_out, int out_size, void* d_ws, size_t ws_size,
                              hipStream_t stream) {
    const float* x  = (const float*)d_in[0];
    const float* Wq = (const float*)d_in[1];
    const float* bq = (const float*)d_in[2];
    const float* Wk = (const float*)d_in[3];
    const float* bk = (const float*)d_in[4];
    const float* Wv = (const float*)d_in[5];
    const float* bv = (const float*)d_in[6];
    const float* Wp = (const float*)d_in[7];
    const float* bp = (const float*)d_in[8];
    float* out = (float*)d_out;

    const size_t n_qkv = (size_t)B_ * H_ * T_ * DH_;   // 4,194,304
    const size_t n_w   = (size_t)DM_ * DM_;            // 1,048,576
    u16* Qb  = (u16*)d_ws;
    u16* Kb  = Qb + n_qkv;
    u16* VTb = Kb + n_qkv;
    u16* Ahb = VTb + n_qkv;
    u16* Alb = Ahb + n_qkv;
    u16* Whb = Alb + n_qkv;
    u16* Wlb = Whb + n_w;

    qkv_mfma<<<32 * 16, 256, 0, stream>>>(x, Wq, bq, Wk, bk, Wv, bv, Qb, Kb, VTb);
    attn_mfma<<<4608, 256, 0, stream>>>(Qb, Kb, VTb, Ahb, Alb, Wp, Whb, Wlb);
    proj_mfma<<<256, 512, 0, stream>>>(Ahb, Alb, Whb, Wlb, bp, out);
}

// Round 15
// 86.974 us; speedup vs baseline: 1.1962x; 1.1962x over previous
//
#include <hip/hip_runtime.h>
#include <hip/hip_bf16.h>

#define B_ 2
#define T_ 2048
#define DM_ 1024
#define H_ 16
#define DH_ 64
// softmax computed in exp2 units: fold log2(e)/sqrt(1024) into Q
#define QSCALE 0.045084220027780106f

typedef unsigned short u16;
typedef unsigned int u32;
typedef __attribute__((ext_vector_type(2))) unsigned int u32x2;
typedef __attribute__((ext_vector_type(4))) unsigned int u32x4;
typedef __attribute__((ext_vector_type(4))) float f32x4v;
typedef __attribute__((ext_vector_type(8))) short bf16x8;
typedef __attribute__((ext_vector_type(4))) float f32x4;
typedef __attribute__((ext_vector_type(16))) float f32x16;

__device__ __forceinline__ u16 f2bf(float f) {
    u32 u = __float_as_uint(f);
    return (u16)((u + 0x7FFF + ((u >> 16) & 1)) >> 16);
}
__device__ __forceinline__ float bf2f(u16 h) {
    return __uint_as_float(((u32)h) << 16);
}
__device__ __forceinline__ float exp2_fast(float x) {
    float r;
    asm("v_exp_f32 %0, %1" : "=v"(r) : "v"(x));
    return r;
}
__device__ __forceinline__ u32 cvtpk_bf16(float lo, float hi) {
    u32 r;
    asm("v_cvt_pk_bf16_f32 %0, %1, %2" : "=v"(r) : "v"(lo), "v"(hi));
    return r;
}

// LDS rows are 128B with 16B-granule XOR swizzle: byte = row*128 + ((c16 ^ (row&7))<<4)
__device__ __forceinline__ const bf16x8* frag_at(const u16* base, int row, int c16) {
    return (const bf16x8*)((const char*)base + row * 128 + ((c16 ^ (row & 7)) << 4));
}

// split 8 f32 -> hi/lo packed u32x4 pairs (element order preserved)
__device__ __forceinline__ void split8(const f32x4v a, const f32x4v b,
                                       u32x4* hi, u32x4* lo) {
    u32x4 h, l;
    h[0] = cvtpk_bf16(a[0], a[1]);
    h[1] = cvtpk_bf16(a[2], a[3]);
    h[2] = cvtpk_bf16(b[0], b[1]);
    h[3] = cvtpk_bf16(b[2], b[3]);
    const float l0 = a[0] - __uint_as_float(h[0] << 16);
    const float l1 = a[1] - __uint_as_float(h[0] & 0xFFFF0000u);
    const float l2 = a[2] - __uint_as_float(h[1] << 16);
    const float l3 = a[3] - __uint_as_float(h[1] & 0xFFFF0000u);
    const float l4 = b[0] - __uint_as_float(h[2] << 16);
    const float l5 = b[1] - __uint_as_float(h[2] & 0xFFFF0000u);
    const float l6 = b[2] - __uint_as_float(h[3] << 16);
    const float l7 = b[3] - __uint_as_float(h[3] & 0xFFFF0000u);
    l[0] = cvtpk_bf16(l0, l1);
    l[1] = cvtpk_bf16(l2, l3);
    l[2] = cvtpk_bf16(l4, l5);
    l[3] = cvtpk_bf16(l6, l7);
    *hi = h; *lo = l;
}

// ---------------- QKV projection via MFMA (split-bf16, fp32-grade) ----------------
// Self-splits Wq/Wk/Wv into LDS; also splits a 2048-elem strip of Wp per block
// (per-thread extra work — hides under W staging + MFMA; no extra blocks/launch).
__global__ __launch_bounds__(256) void qkv_mfma(
    const float* __restrict__ x,
    const float* __restrict__ Wq, const float* __restrict__ bq,
    const float* __restrict__ Wk, const float* __restrict__ bk,
    const float* __restrict__ Wv, const float* __restrict__ bv,
    const float* __restrict__ Wp, u16* __restrict__ Wh, u16* __restrict__ Wl,
    u16* __restrict__ Q, u16* __restrict__ K, u16* __restrict__ VT)
{
    __shared__ u16 Ws[6 * 4096];   // 48KB: Wqh,Wql,Wkh,Wkl,Wvh,Wvl (swizzled rows)

    const int tid = threadIdx.x;
    const int wid = tid >> 6;
    const int lane = tid & 63;
    const int li = lane & 15, g = lane >> 4;

    const int bh = blockIdx.x >> 4;
    const int t0 = (blockIdx.x & 15) * 128;
    const int b = bh >> 4, h = bh & 15;
    const int tw0 = t0 + wid * 32;

    // ---- folded Wp-split: this block's 2048-elem strip, 8 per thread (load early) ----
    const int wpbase = blockIdx.x * 2048 + tid * 8;
    const f32x4v wp0 = *(const f32x4v*)(Wp + wpbase);
    const f32x4v wp1 = *(const f32x4v*)(Wp + wpbase + 4);

    // ---- self-split W staging: 1536 (r,c16) slots, 6 per thread, mat = j>>1 ----
    #pragma unroll
    for (int j = 0; j < 6; ++j) {
        const int idx = (j & 1) * 256 + tid;     // 0..511 within matrix
        const int r = idx >> 3, c16 = idx & 7;
        const float* src = (j < 2) ? Wq : (j < 4) ? Wk : Wv;
        const float* p = src + r * 64 + c16 * 8;
        const f32x4v a = *(const f32x4v*)p;
        const f32x4v bb = *(const f32x4v*)(p + 4);
        u32x4 hv, lv;
        split8(a, bb, &hv, &lv);
        const int dst = r * 128 + ((c16 ^ (r & 7)) << 4);
        const int mat = j >> 1;
        *(u32x4*)((char*)Ws + (2 * mat) * 8192 + dst) = hv;
        *(u32x4*)((char*)Ws + (2 * mat + 1) * 8192 + dst) = lv;
    }

    const float* xb = x + ((size_t)b * T_) * DM_ + h * 64;
    f32x4v xr[2][2][2];
    #pragma unroll
    for (int mt = 0; mt < 2; ++mt)
        #pragma unroll
        for (int kt = 0; kt < 2; ++kt) {
            const float* p = xb + (size_t)(tw0 + 16 * mt + li) * DM_ + kt * 32 + g * 8;
            xr[mt][kt][0] = *(const f32x4v*)p;
            xr[mt][kt][1] = *(const f32x4v*)(p + 4);
        }

    float bq_r[4], bk_r[4], bv_r[4][4];
    #pragma unroll
    for (int nt = 0; nt < 4; ++nt) { bq_r[nt] = bq[16 * nt + li]; bk_r[nt] = bk[16 * nt + li]; }
    #pragma unroll
    for (int vd = 0; vd < 4; ++vd)
        #pragma unroll
        for (int rg = 0; rg < 4; ++rg) bv_r[vd][rg] = bv[16 * vd + 4 * g + rg];

    __syncthreads();   // W split staged (lgkm) + x loads landed

    bf16x8 xhf[2][2], xlf[2][2];
    #pragma unroll
    for (int mt = 0; mt < 2; ++mt)
        #pragma unroll
        for (int kt = 0; kt < 2; ++kt) {
            u32x4 hv, lv;
            split8(xr[mt][kt][0], xr[mt][kt][1], &hv, &lv);
            xhf[mt][kt] = __builtin_bit_cast(bf16x8, hv);
            xlf[mt][kt] = __builtin_bit_cast(bf16x8, lv);
        }

    const u16* Wqh = Ws;
    const u16* Wql = Ws + 4096;
    const u16* Wkh = Ws + 8192;
    const u16* Wkl = Ws + 12288;
    const u16* Wvh = Ws + 16384;
    const u16* Wvl = Ws + 20480;

    const size_t qk_base = ((size_t)bh * T_) * DH_;

    // ---- Q ----
    {
        f32x4 acc[2][4];
        #pragma unroll
        for (int mt = 0; mt < 2; ++mt)
            #pragma unroll
            for (int nt = 0; nt < 4; ++nt) acc[mt][nt] = (f32x4){0.f, 0.f, 0.f, 0.f};
        #pragma unroll
        for (int nt = 0; nt < 4; ++nt)
            #pragma unroll
            for (int kt = 0; kt < 2; ++kt) {
                const bf16x8 wh = *frag_at(Wqh, 16 * nt + li, 4 * kt + g);
                const bf16x8 wl = *frag_at(Wql, 16 * nt + li, 4 * kt + g);
                #pragma unroll
                for (int mt = 0; mt < 2; ++mt) {
                    acc[mt][nt] = __builtin_amdgcn_mfma_f32_16x16x32_bf16(xhf[mt][kt], wh, acc[mt][nt], 0, 0, 0);
                    acc[mt][nt] = __builtin_amdgcn_mfma_f32_16x16x32_bf16(xlf[mt][kt], wh, acc[mt][nt], 0, 0, 0);
                    acc[mt][nt] = __builtin_amdgcn_mfma_f32_16x16x32_bf16(xhf[mt][kt], wl, acc[mt][nt], 0, 0, 0);
                }
            }
        #pragma unroll
        for (int mt = 0; mt < 2; ++mt)
            #pragma unroll
            for (int rg = 0; rg < 4; ++rg) {
                const int t = tw0 + 16 * mt + 4 * g + rg;
                #pragma unroll
                for (int nt = 0; nt < 4; ++nt)
                    Q[qk_base + (size_t)t * DH_ + 16 * nt + li] =
                        f2bf((acc[mt][nt][rg] + bq_r[nt]) * QSCALE);
            }
    }

    // ---- K ----
    {
        f32x4 acc[2][4];
        #pragma unroll
        for (int mt = 0; mt < 2; ++mt)
            #pragma unroll
            for (int nt = 0; nt < 4; ++nt) acc[mt][nt] = (f32x4){0.f, 0.f, 0.f, 0.f};
        #pragma unroll
        for (int nt = 0; nt < 4; ++nt)
            #pragma unroll
            for (int kt = 0; kt < 2; ++kt) {
                const bf16x8 wh = *frag_at(Wkh, 16 * nt + li, 4 * kt + g);
                const bf16x8 wl = *frag_at(Wkl, 16 * nt + li, 4 * kt + g);
                #pragma unroll
                for (int mt = 0; mt < 2; ++mt) {
                    acc[mt][nt] = __builtin_amdgcn_mfma_f32_16x16x32_bf16(xhf[mt][kt], wh, acc[mt][nt], 0, 0, 0);
                    acc[mt][nt] = __builtin_amdgcn_mfma_f32_16x16x32_bf16(xlf[mt][kt], wh, acc[mt][nt], 0, 0, 0);
                    acc[mt][nt] = __builtin_amdgcn_mfma_f32_16x16x32_bf16(xhf[mt][kt], wl, acc[mt][nt], 0, 0, 0);
                }
            }
        #pragma unroll
        for (int mt = 0; mt < 2; ++mt)
            #pragma unroll
            for (int rg = 0; rg < 4; ++rg) {
                const int t = tw0 + 16 * mt + 4 * g + rg;
                #pragma unroll
                for (int nt = 0; nt < 4; ++nt)
                    K[qk_base + (size_t)t * DH_ + 16 * nt + li] =
                        f2bf(acc[mt][nt][rg] + bk_r[nt]);
            }
    }

    // ---- V (swapped) -> V^T ----
    {
        f32x4 acc[4][2];
        #pragma unroll
        for (int vd = 0; vd < 4; ++vd)
            #pragma unroll
            for (int tc = 0; tc < 2; ++tc) acc[vd][tc] = (f32x4){0.f, 0.f, 0.f, 0.f};
        #pragma unroll
        for (int vd = 0; vd < 4; ++vd)
            #pragma unroll
            for (int kt = 0; kt < 2; ++kt) {
                const bf16x8 ah = *frag_at(Wvh, 16 * vd + li, 4 * kt + g);
                const bf16x8 al = *frag_at(Wvl, 16 * vd + li, 4 * kt + g);
                #pragma unroll
                for (int tc = 0; tc < 2; ++tc) {
                    acc[vd][tc] = __builtin_amdgcn_mfma_f32_16x16x32_bf16(ah, xhf[tc][kt], acc[vd][tc], 0, 0, 0);
                    acc[vd][tc] = __builtin_amdgcn_mfma_f32_16x16x32_bf16(al, xhf[tc][kt], acc[vd][tc], 0, 0, 0);
                    acc[vd][tc] = __builtin_amdgcn_mfma_f32_16x16x32_bf16(ah, xlf[tc][kt], acc[vd][tc], 0, 0, 0);
                }
            }
        u16* VTb = VT + (size_t)bh * DH_ * T_;
        #pragma unroll
        for (int vd = 0; vd < 4; ++vd)
            #pragma unroll
            for (int rg = 0; rg < 4; ++rg) {
                const int d = 16 * vd + 4 * g + rg;
                #pragma unroll
                for (int tc = 0; tc < 2; ++tc)
                    VTb[(size_t)d * T_ + tw0 + 16 * tc + li] =
                        f2bf(acc[vd][tc][rg] + bv_r[vd][rg]);
            }
    }

    // ---- folded Wp-split epilogue ----
    {
        u32x4 hv, lv;
        split8(wp0, wp1, &hv, &lv);
        *(u32x4*)(Wh + wpbase) = hv;
        *(u32x4*)(Wl + wpbase) = lv;
    }
}

// ---------------- MFMA flash attention: 32x32, KVBLK=128, no P-LDS (r13) ----------------
// grid = 512 (XCD-swizzled), 4 waves x 32 q-rows. 16 iterations of 128 kv.
__global__ __launch_bounds__(256) void attn_mfma(
    const u16* __restrict__ Q, const u16* __restrict__ K,
    const u16* __restrict__ VT, u16* __restrict__ Ah, u16* __restrict__ Al)
{
    __shared__ char smem[65536];

    const int tid = threadIdx.x;
    const int wid = tid >> 6;              // 0..3
    const int lane = tid & 63;
    const int l = lane & 31, h = lane >> 5;
    const int flat = blockIdx.x;
    const int bh = (flat & 7) + ((flat >> 7) << 3);
    const int qx = (flat >> 3) & 15;
    const int q0 = qx * 128 + wid * 32;

    const size_t bhoff = (size_t)bh * T_ * DH_;

    bf16x8 qf[4];
    {
        const u16* Qp = Q + bhoff + (size_t)(q0 + l) * DH_ + 8 * h;
        #pragma unroll
        for (int kt = 0; kt < 4; ++kt)
            qf[kt] = *(const bf16x8*)(Qp + 16 * kt);
    }

    f32x16 o0 = {}, o1 = {};       // O^T[d][q=l]
    f32x16 sA, sB, sC, sD;
    float l_part = 0.f;

    const char* ldsR[4];
    #pragma unroll
    for (int j = 0; j < 4; ++j)
        ldsR[j] = smem + l * 128 + ((((2 * j + h) ^ (l & 7))) << 4);

    const int sl_r = lane >> 3;
    const int sl_c = (lane & 7) ^ sl_r;
    const char* kgp = (const char*)(K + bhoff) + (32 * wid + sl_r) * 128 + (sl_c << 4);
    const char* vgp = (const char*)(VT + (size_t)bh * DH_ * T_) + (size_t)(16 * wid + sl_r) * (T_ * 2) + (sl_c << 4);
    const int kdst = 32 * wid * 128 + lane * 16;
    const int vdst = 16 * wid * 128 + lane * 16;

#define STAGE(KB_, VB_)                                                                  \
    {                                                                                    \
        _Pragma("unroll")                                                                \
        for (int j = 0; j < 4; ++j)                                                      \
            __builtin_amdgcn_global_load_lds(                                            \
                (const __attribute__((address_space(1))) u32*)(kgp + j * 1024),          \
                (__attribute__((address_space(3))) u32*)(smem + (KB_) + kdst + j * 1024),\
                16, 0, 0);                                                               \
        __builtin_amdgcn_global_load_lds(                                                \
            (const __attribute__((address_space(1))) u32*)vgp,                           \
            (__attribute__((address_space(3))) u32*)(smem + (VB_) + vdst), 16, 0, 0);    \
        __builtin_amdgcn_global_load_lds(                                                \
            (const __attribute__((address_space(1))) u32*)(vgp + 8 * T_ * 2),            \
            (__attribute__((address_space(3))) u32*)(smem + (VB_) + vdst + 1024), 16, 0, 0); \
        __builtin_amdgcn_global_load_lds(                                                \
            (const __attribute__((address_space(1))) u32*)(vgp + 128),                   \
            (__attribute__((address_space(3))) u32*)(smem + (VB_) + 8192 + vdst), 16, 0, 0); \
        __builtin_amdgcn_global_load_lds(                                                \
            (const __attribute__((address_space(1))) u32*)(vgp + 8 * T_ * 2 + 128),      \
            (__attribute__((address_space(3))) u32*)(smem + (VB_) + 8192 + vdst + 1024), 16, 0, 0); \
        kgp += 16384; vgp += 256;                                                        \
    }

#define QK(KB_, S, c)                                                                    \
    {                                                                                    \
        S = (f32x16){};                                                                  \
        _Pragma("unroll")                                                                \
        for (int kt = 0; kt < 4; ++kt) {                                                 \
            const bf16x8 kf = *(const bf16x8*)(ldsR[kt] + (KB_) + (c) * 4096);           \
            S = __builtin_amdgcn_mfma_f32_32x32x16_bf16(kf, qf[kt], S, 0, 0, 0);         \
        }                                                                                \
    }

#define SMPV(S, c, VB_)                                                                  \
    {                                                                                    \
        float lacc = 0.f;                                                                \
        _Pragma("unroll")                                                                \
        for (int r = 0; r < 16; ++r) { S[r] = exp2_fast(S[r]); lacc += S[r]; }           \
        l_part += lacc;                                                                  \
        __builtin_amdgcn_s_setprio(1);                                                   \
        _Pragma("unroll")                                                                \
        for (int ktl = 0; ktl < 2; ++ktl) {                                              \
            const int rb = ktl * 8;                                                      \
            u32 w0 = cvtpk_bf16(S[rb + 0], S[rb + 1]);                                   \
            u32 w1 = cvtpk_bf16(S[rb + 2], S[rb + 3]);                                   \
            u32 w2 = cvtpk_bf16(S[rb + 4], S[rb + 5]);                                   \
            u32 w3 = cvtpk_bf16(S[rb + 6], S[rb + 7]);                                   \
            asm("v_permlane32_swap_b32 %0, %1" : "+v"(w0), "+v"(w2));                    \
            asm("v_permlane32_swap_b32 %0, %1" : "+v"(w1), "+v"(w3));                    \
            u32x4 pw; pw[0] = w0; pw[1] = w1; pw[2] = w2; pw[3] = w3;                    \
            const bf16x8 pf = __builtin_bit_cast(bf16x8, pw);                            \
            const char* vb = ldsR[2 * ((c) & 1) + ktl] + (VB_) + ((c) >> 1) * 8192;      \
            const bf16x8 vf0 = *(const bf16x8*)vb;                                       \
            const bf16x8 vf1 = *(const bf16x8*)(vb + 4096);                              \
            o0 = __builtin_amdgcn_mfma_f32_32x32x16_bf16(vf0, pf, o0, 0, 0, 0);          \
            o1 = __builtin_amdgcn_mfma_f32_32x32x16_bf16(vf1, pf, o1, 0, 0, 0);          \
        }                                                                                \
        __builtin_amdgcn_s_setprio(0);                                                   \
    }

#define ATTN_ITER(KB_, VB_, PKB_, PVB_, DO_PREF)                                         \
    {                                                                                    \
        __syncthreads();                                                                 \
        if (DO_PREF) STAGE(PKB_, PVB_);                                                  \
        __builtin_amdgcn_s_setprio(1);                                                   \
        QK(KB_, sA, 0); QK(KB_, sB, 1); QK(KB_, sC, 2); QK(KB_, sD, 3);                  \
        __builtin_amdgcn_s_setprio(0);                                                   \
        SMPV(sA, 0, VB_); SMPV(sB, 1, VB_); SMPV(sC, 2, VB_); SMPV(sD, 3, VB_);          \
    }

    STAGE(0, 32768);
    for (int it = 0; it < 16; it += 2) {
        ATTN_ITER(0, 32768, 16384, 49152, true);
        ATTN_ITER(16384, 49152, 0, 32768, (it + 2 < 16));
    }
#undef ATTN_ITER
#undef SMPV
#undef QK
#undef STAGE

    const float lt = l_part + __shfl_xor(l_part, 32);
    const float inv = 1.0f / lt;

    __syncthreads();   // done with K/V LDS; reuse as per-wave epilogue scratch

    char* ehi = smem + wid * 8192;
    char* elo = ehi + 4096;
    #pragma unroll
    for (int db = 0; db < 2; ++db) {
        #pragma unroll
        for (int rr = 0; rr < 4; ++rr) {
            float v0, v1, v2, v3;
            if (db == 0) {
                v0 = o0[4 * rr + 0] * inv; v1 = o0[4 * rr + 1] * inv;
                v2 = o0[4 * rr + 2] * inv; v3 = o0[4 * rr + 3] * inv;
            } else {
                v0 = o1[4 * rr + 0] * inv; v1 = o1[4 * rr + 1] * inv;
                v2 = o1[4 * rr + 2] * inv; v3 = o1[4 * rr + 3] * inv;
            }
            u32x2 wh, wl;
            wh.x = cvtpk_bf16(v0, v1);
            wh.y = cvtpk_bf16(v2, v3);
            const float r0 = v0 - __uint_as_float(wh.x << 16);
            const float r1 = v1 - __uint_as_float(wh.x & 0xFFFF0000u);
            const float r2 = v2 - __uint_as_float(wh.y << 16);
            const float r3 = v3 - __uint_as_float(wh.y & 0xFFFF0000u);
            wl.x = cvtpk_bf16(r0, r1);
            wl.y = cvtpk_bf16(r2, r3);
            const int byteoff = l * 128 + (((4 * db + rr) ^ (l & 7)) << 4) + 8 * h;
            *(u32x2*)(ehi + byteoff) = wh;
            *(u32x2*)(elo + byteoff) = wl;
        }
    }
    // per-wave private region: lgkmcnt ordering suffices, no barrier

    const int b = bh >> 4, head = bh & 15;
    const int sub = lane & 7;
    const int row8 = lane >> 3;
    #pragma unroll
    for (int rr = 0; rr < 4; ++rr) {
        const int row = 8 * rr + row8;
        const int byteoff = row * 128 + ((sub ^ row8) << 4);
        const size_t gidx = ((size_t)b * T_ + q0 + row) * DM_ + head * 64 + sub * 8;
        *(u32x4*)(Ah + gidx) = *(const u32x4*)(ehi + byteoff);
        *(u32x4*)(Al + gidx) = *(const u32x4*)(elo + byteoff);
    }
}

// ---------------- Output projection: split-bf16 MFMA GEMM, 8 waves, dbuf ----------------
// 1-D grid 256, XCD-swizzled: col strip = flat&7 (W strip stays L2-resident per XCD).
__global__ __launch_bounds__(512) void proj_mfma(
    const u16* __restrict__ Ah, const u16* __restrict__ Al,
    const u16* __restrict__ Wh, const u16* __restrict__ Wl,
    const float* __restrict__ bp, float* __restrict__ out)
{
    __shared__ char smem[131072];  // 2 x {Ah,Al,Wh,Wl} of 128x64 bf16 (16KB each)

    const int tid = threadIdx.x;
    const int wid = tid >> 6;      // 0..7
    const int lane = tid & 63;
    const int li = lane & 15, g = lane >> 4;
    const int flat = blockIdx.x;
    const int row0 = (flat >> 3) * 128, col0 = (flat & 7) * 128;

    const int mat = wid >> 1, half = wid & 1;
    const char* gsrc;
    if (mat == 0)      gsrc = (const char*)(Ah + (size_t)row0 * DM_);
    else if (mat == 1) gsrc = (const char*)(Al + (size_t)row0 * DM_);
    else if (mat == 2) gsrc = (const char*)(Wh + (size_t)col0 * DM_);
    else               gsrc = (const char*)(Wl + (size_t)col0 * DM_);
    const int r_local = half * 64 + (lane >> 3);
    const int c16s = (lane & 7) ^ (lane >> 3);
    const char* gp0 = gsrc + (size_t)r_local * (DM_ * 2) + (c16s << 4);
    const int ldst0 = mat * 16384 + half * 8192;

#define PSTAGE(BUF, STEP)                                                                \
    {                                                                                    \
        _Pragma("unroll")                                                                \
        for (int j = 0; j < 8; ++j) {                                                    \
            __builtin_amdgcn_global_load_lds(                                            \
                (const __attribute__((address_space(1))) u32*)(gp0 + (size_t)(STEP) * 128 + (size_t)j * (8 * DM_ * 2)), \
                (__attribute__((address_space(3))) u32*)(smem + (BUF) + ldst0 + j * 1024),\
                16, 0, 0);                                                               \
        }                                                                                \
    }

    const int wr = wid >> 1, wc = wid & 1;

    f32x4 acc[2][4];
    #pragma unroll
    for (int m = 0; m < 2; ++m)
        #pragma unroll
        for (int n = 0; n < 4; ++n) acc[m][n] = (f32x4){0.f, 0.f, 0.f, 0.f};

    PSTAGE(0, 0);
    for (int step = 0; step < 16; ++step) {
        const int buf = (step & 1) * 65536;
        __syncthreads();
        if (step < 15) PSTAGE(buf ^ 65536, step + 1);

        const u16* pAh = (const u16*)(smem + buf);
        const u16* pAl = (const u16*)(smem + buf + 16384);
        const u16* pWh = (const u16*)(smem + buf + 32768);
        const u16* pWl = (const u16*)(smem + buf + 49152);

        __builtin_amdgcn_s_setprio(1);
        #pragma unroll
        for (int kt = 0; kt < 2; ++kt) {
            bf16x8 ah[2], al[2], wh[4], wl[4];
            #pragma unroll
            for (int m = 0; m < 2; ++m) {
                ah[m] = *frag_at(pAh, wr * 32 + m * 16 + li, kt * 4 + g);
                al[m] = *frag_at(pAl, wr * 32 + m * 16 + li, kt * 4 + g);
            }
            #pragma unroll
            for (int n = 0; n < 4; ++n) {
                wh[n] = *frag_at(pWh, wc * 64 + n * 16 + li, kt * 4 + g);
                wl[n] = *frag_at(pWl, wc * 64 + n * 16 + li, kt * 4 + g);
            }
            #pragma unroll
            for (int m = 0; m < 2; ++m)
                #pragma unroll
                for (int n = 0; n < 4; ++n) {
                    acc[m][n] = __builtin_amdgcn_mfma_f32_16x16x32_bf16(ah[m], wh[n], acc[m][n], 0, 0, 0);
                    acc[m][n] = __builtin_amdgcn_mfma_f32_16x16x32_bf16(al[m], wh[n], acc[m][n], 0, 0, 0);
                    acc[m][n] = __builtin_amdgcn_mfma_f32_16x16x32_bf16(ah[m], wl[n], acc[m][n], 0, 0, 0);
                }
        }
        __builtin_amdgcn_s_setprio(0);
    }
#undef PSTAGE

    const int orow = row0 + wr * 32;
    const int ocol = col0 + wc * 64;
    float bias[4];
    #pragma unroll
    for (int n = 0; n < 4; ++n) bias[n] = bp[ocol + n * 16 + li];
    #pragma unroll
    for (int m = 0; m < 2; ++m)
        #pragma unroll
        for (int n = 0; n < 4; ++n)
            #pragma unroll
            for (int q = 0; q < 4; ++q)
                out[(size_t)(orow + m * 16 + g * 4 + q) * DM_ + ocol + n * 16 + li] =
                    acc[m][n][q] + bias[n];
}

extern "C" void kernel_launch(void* const* d_in, const int* in_sizes, int n_in,
                              void* d_out, int out_size, void* d_ws, size_t ws_size,
                              hipStream_t stream) {
    const float* x  = (const float*)d_in[0];
    const float* Wq = (const float*)d_in[1];
    const float* bq = (const float*)d_in[2];
    const float* Wk = (const float*)d_in[3];
    const float* bk = (const float*)d_in[4];
    const float* Wv = (const float*)d_in[5];
    const float* bv = (const float*)d_in[6];
    const float* Wp = (const float*)d_in[7];
    const float* bp = (const float*)d_in[8];
    float* out = (float*)d_out;

    const size_t n_qkv = (size_t)B_ * H_ * T_ * DH_;   // 4,194,304
    const size_t n_w   = (size_t)DM_ * DM_;            // 1,048,576
    u16* Qb  = (u16*)d_ws;
    u16* Kb  = Qb + n_qkv;
    u16* VTb = Kb + n_qkv;
    u16* Ahb = VTb + n_qkv;
    u16* Alb = Ahb + n_qkv;
    u16* Whb = Alb + n_qkv;
    u16* Wlb = Whb + n_w;

    qkv_mfma<<<32 * 16, 256, 0, stream>>>(x, Wq, bq, Wk, bk, Wv, bv, Wp, Whb, Wlb, Qb, Kb, VTb);
    attn_mfma<<<512, 256, 0, stream>>>(Qb, Kb, VTb, Ahb, Alb);
    proj_mfma<<<256, 512, 0, stream>>>(Ahb, Alb, Whb, Wlb, bp, out);
}